// Round 1
// 433.610 us; speedup vs baseline: 1.0255x; 1.0255x over previous
//
#include <hip/hip_runtime.h>
#include <hip/hip_bf16.h>

// Problem constants (B, C, H, W, K) = (16, 512, 64, 64, 32)
#define BB   16
#define CC   512
#define HWN  4096        // H*W
#define KK   32
#define EPSF 1e-5f

typedef short bf16x8 __attribute__((ext_vector_type(8)));
typedef float f32x4  __attribute__((ext_vector_type(4)));

#define MFMA16 __builtin_amdgcn_mfma_f32_16x16x32_bf16

// async global->LDS, 16B per lane. LDS dest = wave-uniform base + lane*16.
#define GLD16(g, l) __builtin_amdgcn_global_load_lds(                          \
    (const __attribute__((address_space(1))) void*)(g),                        \
    (__attribute__((address_space(3))) void*)(l), 16, 0, 0)

// conv epilogue LDS tile addressing: [o][n] stride 136 shorts, 8-short chunks
// XOR-swizzled by (o>>3) so column sweeps spread across banks.
#define EADDR(o, n) ((o) * 136 + (((((n) >> 3) ^ (((o) >> 3) & 15))) << 3) + ((n) & 7))

static __device__ __forceinline__ unsigned short f2b(float f) {
    unsigned u = __builtin_bit_cast(unsigned, f);
    unsigned r = (u + 0x7FFFu + ((u >> 16) & 1u)) >> 16;   // RNE
    return (unsigned short)r;
}

// ---------------- K0: weight conversions + small precomputes ----------------
__global__ __launch_bounds__(256) void k_prep(const float* __restrict__ W,
                                              const float* __restrict__ cw,
                                              const float* __restrict__ scale,
                                              const float* __restrict__ g1,
                                              const float* __restrict__ b1,
                                              const float* __restrict__ m1,
                                              const float* __restrict__ v1,
                                              unsigned short* __restrict__ Wb,
                                              unsigned short* __restrict__ cwb,
                                              float* __restrict__ sc2,
                                              float* __restrict__ s1,
                                              float* __restrict__ t1) {
    int bid = blockIdx.x, t = threadIdx.x;
    if (bid < 256) {                       // conv_w fp32 -> bf16 (262144 elems)
        int i = (bid * 256 + t) * 4;
        float4 v = *(const float4*)(W + i);
        uint2 p;
        p.x = (unsigned)f2b(v.x) | ((unsigned)f2b(v.y) << 16);
        p.y = (unsigned)f2b(v.z) | ((unsigned)f2b(v.w) << 16);
        *(uint2*)(Wb + i) = p;
    } else if (bid < 272) {                // codewords fp32 -> bf16 (16384 elems)
        int i = ((bid - 256) * 256 + t) * 4;
        float4 v = *(const float4*)(cw + i);
        uint2 p;
        p.x = (unsigned)f2b(v.x) | ((unsigned)f2b(v.y) << 16);
        p.y = (unsigned)f2b(v.z) | ((unsigned)f2b(v.w) << 16);
        *(uint2*)(cwb + i) = p;
    } else {                               // sc2[k] = scale*||c_k||^2 ; bn1 affine
        int k = t >> 3, l8 = t & 7;
        const float* row = cw + k * CC + l8 * 64;
        float s = 0.f;
#pragma unroll
        for (int i = 0; i < 16; i++) {
            float4 c4 = *(const float4*)(row + i * 4);
            s += c4.x * c4.x + c4.y * c4.y + c4.z * c4.z + c4.w * c4.w;
        }
        s += __shfl_xor(s, 1); s += __shfl_xor(s, 2); s += __shfl_xor(s, 4);
        if (l8 == 0) sc2[k] = scale[k] * s;
        if (t < KK) {
            float sv = rsqrtf(v1[t] + EPSF) * g1[t];
            s1[t] = sv;
            t1[t] = b1[t] - m1[t] * sv;
        }
    }
}

// ---------------- K1a: x (B,C,N) fp32 -> xT (B,N,C) bf16 --------------------
__global__ __launch_bounds__(256) void k_transpose(const float* __restrict__ x,
                                                   unsigned short* __restrict__ xT) {
    __shared__ float tile[64][65];
    int bid = blockIdx.x;
    int b   = bid >> 9;
    int rem = bid & 511;
    int c0  = (rem >> 6) * 64;
    int n0  = (rem & 63) * 64;
    int t = threadIdx.x;
#pragma unroll
    for (int p = 0; p < 4; p++) {
        int s = p * 256 + t;
        int row = s >> 4, col = (s & 15) * 4;
        float4 v = *(const float4*)(x + (size_t)(b * CC + c0 + row) * HWN + n0 + col);
        tile[row][col]     = v.x;
        tile[row][col + 1] = v.y;
        tile[row][col + 2] = v.z;
        tile[row][col + 3] = v.w;
    }
    __syncthreads();
    int nr = t >> 2;
    int cg = (t & 3) * 16;
    unsigned u[8];
#pragma unroll
    for (int j = 0; j < 8; j++) {
        u[j] = (unsigned)f2b(tile[cg + 2 * j][nr]) |
               ((unsigned)f2b(tile[cg + 2 * j + 1][nr]) << 16);
    }
    unsigned short* dst = xT + (size_t)(b * HWN + n0 + nr) * CC + c0 + cg;
    uint4 a; a.x = u[0]; a.y = u[1]; a.z = u[2]; a.w = u[3];
    uint4 c; c.x = u[4]; c.y = u[5]; c.z = u[6]; c.w = u[7];
    *(uint4*)(dst)     = a;
    *(uint4*)(dst + 8) = c;
}

// ---------------- K1b: conv GEMM + BN2 + ReLU -> feats, featsT, x2 ----------
// Pipelined: BK=32 panels x16, double-buffered LDS staging, counted vmcnt,
// raw s_barrier pairs. Staging buffers: A@[0,16KB), B@[16KB,32KB) bytes;
// epilogue 128x136 tile (34816B) reuses the same LDS after the loop.
__global__ __launch_bounds__(256) void k_conv_gemm(const unsigned short* __restrict__ xT,
                                                   const unsigned short* __restrict__ Wb,
                                                   const float* __restrict__ g2,
                                                   const float* __restrict__ b2,
                                                   const float* __restrict__ m2,
                                                   const float* __restrict__ v2,
                                                   unsigned short* __restrict__ feats,
                                                   unsigned short* __restrict__ featsT,
                                                   float* __restrict__ x2) {
    __shared__ __align__(16) short lds[17408];
    int bid = blockIdx.x;
    // XCD-contiguous swizzle: 2048 blocks, 8 XCDs -> 256-block contiguous chunks.
    // Blocks sharing an A-stripe (same b,m0; consecutive logical ids) stay on one XCD.
    bid = (bid & 7) * 256 + (bid >> 3);
    int b   = bid >> 7;
    int rem = bid & 127;
    int m0  = (rem >> 2) * 128;   // spatial n base
    int o0  = (rem & 3) * 128;    // out-channel base fastest -> L2 reuse of xT stripe
    int t = threadIdx.x, lane = t & 63, wave = t >> 6;
    int mb = (wave >> 1) * 64, ob = (wave & 1) * 64;
    int col_l = lane & 15, quad = lane >> 4;

    f32x4 zero = {0.f, 0.f, 0.f, 0.f};
    f32x4 acc[4][4];
#pragma unroll
    for (int i = 0; i < 4; i++)
#pragma unroll
        for (int j = 0; j < 4; j++) acc[i][j] = zero;

    const unsigned short* Abase = xT + (size_t)(b * HWN + m0) * CC;
    const unsigned short* Bbase = Wb + (size_t)o0 * CC;

#define CSTAGE(pp, bb) do {                                                   \
    int c0_ = (pp) * 32;                                                      \
    _Pragma("unroll")                                                         \
    for (int p2 = 0; p2 < 2; p2++) {                                          \
        int sbase = p2 * 256 + wave * 64;                                     \
        int s = sbase + lane;                                                 \
        int row = s >> 2, part = (s & 3) * 8;                                 \
        GLD16(Abase + (size_t)row * CC + c0_ + part,                          \
              (char*)lds + (bb) * 8192 + sbase * 16);                         \
        GLD16(Bbase + (size_t)row * CC + c0_ + part,                          \
              (char*)lds + 16384 + (bb) * 8192 + sbase * 16);                 \
    } } while (0)

#define CCOMP(bb) do {                                                        \
    bf16x8 af[4], bfv[4];                                                     \
    _Pragma("unroll")                                                         \
    for (int im = 0; im < 4; im++)                                            \
        af[im] = *(const bf16x8*)(&lds[(bb) * 4096 + (mb + im * 16 + col_l) * 32 + quad * 8]); \
    _Pragma("unroll")                                                         \
    for (int in = 0; in < 4; in++)                                            \
        bfv[in] = *(const bf16x8*)(&lds[8192 + (bb) * 4096 + (ob + in * 16 + col_l) * 32 + quad * 8]); \
    _Pragma("unroll")                                                         \
    for (int im = 0; im < 4; im++)                                            \
        _Pragma("unroll")                                                     \
        for (int in = 0; in < 4; in++)                                        \
            acc[im][in] = MFMA16(af[im], bfv[in], acc[im][in], 0, 0, 0);      \
    } while (0)

    CSTAGE(0, 0);
    for (int p = 0; p < 15; p++) {
        CSTAGE(p + 1, (p + 1) & 1);                      // prefetch next panel
        asm volatile("s_waitcnt vmcnt(4)" ::: "memory"); // panel p landed (next 4 in flight)
        __builtin_amdgcn_s_barrier();                    // all waves' panel-p writes visible
        asm volatile("" ::: "memory");
        CCOMP(p & 1);
        asm volatile("s_waitcnt lgkmcnt(0)" ::: "memory"); // my ds_reads drained
        __builtin_amdgcn_s_barrier();                    // buffer (p&1) free for p+2's stage
    }
    asm volatile("s_waitcnt vmcnt(0)" ::: "memory");
    __builtin_amdgcn_s_barrier();
    asm volatile("" ::: "memory");
    CCOMP(1);                                            // panel 15
    __syncthreads();                                     // all reads done before LDS reuse

    // ---- Epilogue: BN2+ReLU; scatter to LDS tile; x2 from registers ----
    float scv[4], offv[4];
#pragma unroll
    for (int in = 0; in < 4; in++) {
        int o = o0 + ob + in * 16 + col_l;
        float sv = rsqrtf(v2[o] + EPSF) * g2[o];
        scv[in]  = sv;
        offv[in] = b2[o] - m2[o] * sv;
    }
#pragma unroll
    for (int im = 0; im < 4; im++) {
        int n_l = mb + im * 16 + quad * 4;
        float vv[4][4];
#pragma unroll
        for (int in = 0; in < 4; in++)
#pragma unroll
            for (int r = 0; r < 4; r++)
                vv[in][r] = fmaxf(acc[im][in][r] * scv[in] + offv[in], 0.f);
#pragma unroll
        for (int in = 0; in < 4; in++) {
            int o_l = ob + in * 16 + col_l;
            uint2 pk;
            pk.x = (unsigned)f2b(vv[in][0]) | ((unsigned)f2b(vv[in][1]) << 16);
            pk.y = (unsigned)f2b(vv[in][2]) | ((unsigned)f2b(vv[in][3]) << 16);
            *(uint2*)(&lds[EADDR(o_l, n_l)]) = pk;
        }
#pragma unroll
        for (int r = 0; r < 4; r++) {
            float ss = vv[0][r] * vv[0][r] + vv[1][r] * vv[1][r] +
                       vv[2][r] * vv[2][r] + vv[3][r] * vv[3][r];
            ss += __shfl_xor(ss, 1); ss += __shfl_xor(ss, 2);
            ss += __shfl_xor(ss, 4); ss += __shfl_xor(ss, 8);
            if (col_l == 0) atomicAdd(&x2[b * HWN + m0 + n_l + r], ss);
        }
    }
    __syncthreads();

    // ---- featsT sweep: coalesced 256B rows (o-major) ----
#pragma unroll
    for (int rr = 0; rr < 8; rr++) {
        int o = rr * 16 + (t >> 4);
        int n16 = t & 15;
        uint4 v = *(const uint4*)(&lds[EADDR(o, n16 * 8)]);
        *(uint4*)(featsT + (size_t)(b * CC + o0 + o) * HWN + m0 + n16 * 8) = v;
    }
    // ---- feats sweep: coalesced 256B rows (n-major) ----
#pragma unroll
    for (int rr = 0; rr < 8; rr++) {
        int n = rr * 16 + (t >> 4);
        int o16 = t & 15;
        unsigned u[4];
#pragma unroll
        for (int jj = 0; jj < 4; jj++) {
            unsigned short a = lds[EADDR(o16 * 8 + 2 * jj,     n)];
            unsigned short bsh = lds[EADDR(o16 * 8 + 2 * jj + 1, n)];
            u[jj] = (unsigned)a | ((unsigned)bsh << 16);
        }
        uint4 pk; pk.x = u[0]; pk.y = u[1]; pk.z = u[2]; pk.w = u[3];
        *(uint4*)(feats + (size_t)(b * HWN + m0 + n) * CC + o0 + o16 * 8) = pk;
    }
}

// ---------------- K2: fused xc^T GEMM + softmax -> assignT bf16, asum -------
// Pipelined: dbuf feats staging, counted vmcnt(2), raw barriers.
__global__ __launch_bounds__(256) void k_assign(const unsigned short* __restrict__ feats,
                                                const unsigned short* __restrict__ cwb,
                                                const float* __restrict__ x2,
                                                const float* __restrict__ scale,
                                                const float* __restrict__ sc2,
                                                unsigned short* __restrict__ assignT,
                                                float* __restrict__ asum) {
    // cwl (32x520 padded) @ shorts [0,16640); fl dbuf @ shorts 16640 + bb*4096
    __shared__ __align__(16) short lds2[24832];
    __shared__ float sl[KK], cl[KK];
    int bid = blockIdx.x;
    int b = bid >> 5, n0 = (bid & 31) * 128;
    int t = threadIdx.x, lane = t & 63, wave = t >> 6;
    int col_l = lane & 15, quad = lane >> 4;

    // stage all of cw (bf16, 32x512) into padded LDS once
#pragma unroll
    for (int p = 0; p < 8; p++) {
        int s = p * 256 + t;             // 2048 chunks of 8 shorts
        int row = s >> 6, c8 = (s & 63) * 8;
        *(uint4*)(&lds2[row * 520 + c8]) = *(const uint4*)(cwb + row * 512 + c8);
    }
    if (t < KK) { sl[t] = scale[t]; cl[t] = sc2[t]; }

    f32x4 zero = {0.f, 0.f, 0.f, 0.f};
    f32x4 acc[2][2];                     // [k-tile mk][n col-tile ct]
    acc[0][0] = zero; acc[0][1] = zero; acc[1][0] = zero; acc[1][1] = zero;

    const unsigned short* Fbase = feats + (size_t)(b * HWN + n0) * CC;

#define ASTAGE(ci_, bb) do {                                                  \
    int c0_ = (ci_) * 32;                                                     \
    _Pragma("unroll")                                                         \
    for (int p2 = 0; p2 < 2; p2++) {                                          \
        int sbase = p2 * 256 + wave * 64;                                     \
        int s = sbase + lane;                                                 \
        GLD16(Fbase + (size_t)(s >> 2) * CC + c0_ + (s & 3) * 8,              \
              (char*)lds2 + 33280 + (bb) * 8192 + sbase * 16);                \
    } } while (0)

#define ACOMP(ci_, bb) do {                                                   \
    int c0_ = (ci_) * 32;                                                     \
    bf16x8 af0 = *(const bf16x8*)(&lds2[(col_l) * 520 + c0_ + quad * 8]);     \
    bf16x8 af1 = *(const bf16x8*)(&lds2[(16 + col_l) * 520 + c0_ + quad * 8]);\
    _Pragma("unroll")                                                         \
    for (int ct = 0; ct < 2; ct++) {                                          \
        bf16x8 bf = *(const bf16x8*)(&lds2[16640 + (bb) * 4096 +              \
                     (wave * 32 + ct * 16 + col_l) * 32 + quad * 8]);         \
        acc[0][ct] = MFMA16(af0, bf, acc[0][ct], 0, 0, 0);                    \
        acc[1][ct] = MFMA16(af1, bf, acc[1][ct], 0, 0, 0);                    \
    } } while (0)

    ASTAGE(0, 0);
    asm volatile("s_waitcnt lgkmcnt(0)" ::: "memory");   // cwl/sl/cl writes done
    for (int ci = 0; ci < 15; ci++) {
        ASTAGE(ci + 1, (ci + 1) & 1);
        asm volatile("s_waitcnt vmcnt(2)" ::: "memory");
        __builtin_amdgcn_s_barrier();
        asm volatile("" ::: "memory");
        ACOMP(ci, ci & 1);
        asm volatile("s_waitcnt lgkmcnt(0)" ::: "memory");
        __builtin_amdgcn_s_barrier();
    }
    asm volatile("s_waitcnt vmcnt(0)" ::: "memory");
    __builtin_amdgcn_s_barrier();
    asm volatile("" ::: "memory");
    ACOMP(15, 1);

    // softmax over k per n column; write assignT; accumulate asum
    float asw[2][4];
#pragma unroll
    for (int mk = 0; mk < 2; mk++)
#pragma unroll
        for (int r = 0; r < 4; r++) asw[mk][r] = 0.f;

#pragma unroll
    for (int ct = 0; ct < 2; ct++) {
        int n = n0 + wave * 32 + ct * 16 + col_l;
        float x2v = x2[b * HWN + n];
        float d[2][4];
        float mmax = -3.4e38f;
#pragma unroll
        for (int mk = 0; mk < 2; mk++)
#pragma unroll
            for (int r = 0; r < 4; r++) {
                int k = mk * 16 + quad * 4 + r;
                d[mk][r] = sl[k] * (x2v - 2.f * acc[mk][ct][r]) + cl[k];
                mmax = fmaxf(mmax, d[mk][r]);
            }
        mmax = fmaxf(mmax, __shfl_xor(mmax, 16));
        mmax = fmaxf(mmax, __shfl_xor(mmax, 32));
        float ssum = 0.f;
#pragma unroll
        for (int mk = 0; mk < 2; mk++)
#pragma unroll
            for (int r = 0; r < 4; r++) {
                d[mk][r] = __expf(d[mk][r] - mmax);
                ssum += d[mk][r];
            }
        ssum += __shfl_xor(ssum, 16);
        ssum += __shfl_xor(ssum, 32);
        float rinv = 1.f / ssum;
#pragma unroll
        for (int mk = 0; mk < 2; mk++)
#pragma unroll
            for (int r = 0; r < 4; r++) {
                int k = mk * 16 + quad * 4 + r;
                float a = d[mk][r] * rinv;
                assignT[(size_t)(b * KK + k) * HWN + n] = f2b(a);
                float p = a;
                p += __shfl_xor(p, 1); p += __shfl_xor(p, 2);
                p += __shfl_xor(p, 4); p += __shfl_xor(p, 8);
                asw[mk][r] += p;       // valid on col_l==0 lanes
            }
    }
#pragma unroll
    for (int mk = 0; mk < 2; mk++)
#pragma unroll
        for (int r = 0; r < 4; r++)
            if (col_l == 0)
                atomicAdd(&asum[b * KK + mk * 16 + quad * 4 + r], asw[mk][r]);
}

// ---------------- K3: encode GEMM: enc[b,c,k] += sum_n a[k,n] fT[c,n] -------
// Pipelined: dbuf A/B staging (40KB), counted vmcnt(5), raw barriers.
__global__ __launch_bounds__(256) void k_encode(const unsigned short* __restrict__ featsT,
                                                const unsigned short* __restrict__ assignT,
                                                float* __restrict__ enc) {
    // Al: bytes bb*16384 + pc*8192 (2 buf x 2 panels x 8KB = 32KB)
    // Bl: bytes 32768 + bb*4096 + pc*2048 (2 buf x 2 panels x 2KB = 8KB)
    __shared__ __align__(16) short lds3[20480];
    int bid = blockIdx.x;
    int b   = bid >> 5;
    int rem = bid & 31;
    int c0  = (rem >> 3) * 128;
    int ns  = rem & 7;                   // n-split: [ns*512, ns*512+512)
    int t = threadIdx.x, lane = t & 63, wave = t >> 6;
    int col_l = lane & 15, quad = lane >> 4;

    f32x4 zero = {0.f, 0.f, 0.f, 0.f};
    f32x4 acc[2][2];                     // [c-subtile][k col-tile]
    acc[0][0] = zero; acc[0][1] = zero; acc[1][0] = zero; acc[1][1] = zero;

    const unsigned short* Abase = featsT + (size_t)(b * CC + c0) * HWN;
    const unsigned short* Bbase = assignT + (size_t)(b * KK) * HWN;

#define ESTAGE(it_, bb) do {                                                  \
    int n0_ = ns * 512 + (it_) * 64;                                          \
    _Pragma("unroll")                                                         \
    for (int pc = 0; pc < 2; pc++)                                            \
        _Pragma("unroll")                                                     \
        for (int p2 = 0; p2 < 2; p2++) {                                      \
            int sbase = p2 * 256 + wave * 64;                                 \
            int s = sbase + lane;                                             \
            GLD16(Abase + (size_t)(s >> 2) * HWN + n0_ + pc * 32 + (s & 3) * 8, \
                  (char*)lds3 + (bb) * 16384 + pc * 8192 + sbase * 16);       \
        }                                                                     \
    {   int s = t;                                                            \
        int pan = s >> 7, row = (s & 127) >> 2, part = (s & 3) * 8;           \
        GLD16(Bbase + (size_t)row * HWN + n0_ + pan * 32 + part,              \
              (char*)lds3 + 32768 + (bb) * 4096 +                             \
              ((wave >> 1) * 2048 + (wave & 1) * 1024) + lane * 16);          \
    } } while (0)

#define ECOMP(bb) do {                                                        \
    _Pragma("unroll")                                                         \
    for (int pc = 0; pc < 2; pc++) {                                          \
        bf16x8 a0 = *(const bf16x8*)(&lds3[(bb) * 8192 + pc * 4096 + (wave * 32 + col_l) * 32 + quad * 8]); \
        bf16x8 a1 = *(const bf16x8*)(&lds3[(bb) * 8192 + pc * 4096 + (wave * 32 + 16 + col_l) * 32 + quad * 8]); \
        bf16x8 b0 = *(const bf16x8*)(&lds3[16384 + (bb) * 2048 + pc * 1024 + (col_l) * 32 + quad * 8]); \
        bf16x8 b1 = *(const bf16x8*)(&lds3[16384 + (bb) * 2048 + pc * 1024 + (16 + col_l) * 32 + quad * 8]); \
        acc[0][0] = MFMA16(a0, b0, acc[0][0], 0, 0, 0);                       \
        acc[0][1] = MFMA16(a0, b1, acc[0][1], 0, 0, 0);                       \
        acc[1][0] = MFMA16(a1, b0, acc[1][0], 0, 0, 0);                       \
        acc[1][1] = MFMA16(a1, b1, acc[1][1], 0, 0, 0);                       \
    } } while (0)

    ESTAGE(0, 0);
    for (int it = 0; it < 7; it++) {
        ESTAGE(it + 1, (it + 1) & 1);
        asm volatile("s_waitcnt vmcnt(5)" ::: "memory");
        __builtin_amdgcn_s_barrier();
        asm volatile("" ::: "memory");
        ECOMP(it & 1);
        asm volatile("s_waitcnt lgkmcnt(0)" ::: "memory");
        __builtin_amdgcn_s_barrier();
    }
    asm volatile("s_waitcnt vmcnt(0)" ::: "memory");
    __builtin_amdgcn_s_barrier();
    asm volatile("" ::: "memory");
    ECOMP(1);

#pragma unroll
    for (int i2 = 0; i2 < 2; i2++)
#pragma unroll
        for (int ck = 0; ck < 2; ck++)
#pragma unroll
            for (int r = 0; r < 4; r++) {
                int c = c0 + wave * 32 + i2 * 16 + quad * 4 + r;
                int k = ck * 16 + col_l;
                atomicAdd(&enc[(size_t)(b * CC + c) * KK + k], acc[i2][ck][r]);
            }
}

// ---------------- K3b: BN1 + ReLU + mean over k -> efeat --------------------
__global__ __launch_bounds__(256) void k_efeat(const float* __restrict__ enc,
                                               const float* __restrict__ asum,
                                               const float* __restrict__ cwf,
                                               const float* __restrict__ s1,
                                               const float* __restrict__ t1,
                                               float* __restrict__ efeat) {
    __shared__ float asl[KK], s1l[KK], t1l[KK];
    int b = blockIdx.x, t = threadIdx.x;
    if (t < KK) { asl[t] = asum[b * KK + t]; s1l[t] = s1[t]; t1l[t] = t1[t]; }
    __syncthreads();
#pragma unroll
    for (int cc = 0; cc < 2; cc++) {
        int c = cc * 256 + t;
        const float* er = enc + (size_t)(b * CC + c) * KK;
        float s = 0.f;
#pragma unroll
        for (int k = 0; k < KK; k++) {
            float v = (er[k] - asl[k] * cwf[k * CC + c]) * s1l[k] + t1l[k];
            s += fmaxf(v, 0.f);
        }
        efeat[b * CC + c] = s * (1.f / 32.f);
    }
}

// ---------------- K4: gamma = sigmoid(efeat @ fc_w^T + fc_b) ----------------
__global__ __launch_bounds__(256) void k_fc(const float* __restrict__ efeat,
                                            const float* __restrict__ fcw,
                                            const float* __restrict__ fcb,
                                            float* __restrict__ gamma) {
    __shared__ float ef[CC];
    int bid = blockIdx.x;
    int b  = bid >> 1;
    int o0 = (bid & 1) * 256;
    int t = threadIdx.x;
    if (t < 128) *(float4*)(&ef[t * 4]) = *(const float4*)(efeat + b * CC + t * 4);
    __syncthreads();
    int o = o0 + t;
    float a = fcb[o];
    const float* wrow = fcw + (size_t)o * CC;
#pragma unroll 4
    for (int c4 = 0; c4 < 128; c4++) {
        float4 w = *(const float4*)(wrow + c4 * 4);
        float4 e = *(const float4*)(&ef[c4 * 4]);
        a += w.x * e.x + w.y * e.y + w.z * e.z + w.w * e.w;
    }
    gamma[b * CC + o] = 1.f / (1.f + __expf(-a));
}

// ---------------- K5: out = relu(x * (1 + gamma[b,c])) ----------------------
// one block per (b,c) row of 4096 floats
__global__ __launch_bounds__(256) void k_gate(const float* __restrict__ x,
                                              const float* __restrict__ gamma,
                                              float* __restrict__ out) {
    int bid = blockIdx.x;                // bid = b*512 + c
    float g = 1.f + gamma[bid];
    const float* xr = x + ((size_t)bid << 12);
    float* orow = out + ((size_t)bid << 12);
    int t4 = threadIdx.x * 4;
#pragma unroll
    for (int u = 0; u < 4; u++) {
        float4 v = *(const float4*)(xr + u * 1024 + t4);
        v.x = fmaxf(v.x * g, 0.f);
        v.y = fmaxf(v.y * g, 0.f);
        v.z = fmaxf(v.z * g, 0.f);
        v.w = fmaxf(v.w * g, 0.f);
        *(float4*)(orow + u * 1024 + t4) = v;
    }
}

extern "C" void kernel_launch(void* const* d_in, const int* in_sizes, int n_in,
                              void* d_out, int out_size, void* d_ws, size_t ws_size,
                              hipStream_t stream) {
    const float* x      = (const float*)d_in[0];
    const float* conv_w = (const float*)d_in[1];
    const float* bn2_g  = (const float*)d_in[2];
    const float* bn2_b  = (const float*)d_in[3];
    const float* bn2_m  = (const float*)d_in[4];
    const float* bn2_v  = (const float*)d_in[5];
    const float* cw     = (const float*)d_in[6];
    const float* scale  = (const float*)d_in[7];
    const float* bn1_g  = (const float*)d_in[8];
    const float* bn1_b  = (const float*)d_in[9];
    const float* bn1_m  = (const float*)d_in[10];
    const float* bn1_v  = (const float*)d_in[11];
    const float* fc_w   = (const float*)d_in[12];
    const float* fc_b   = (const float*)d_in[13];

    float* outf = (float*)d_out;               // [0,8192) efeat, [8192,...) gated output
    char* ws = (char*)d_ws;

    // workspace layout (x2/asum/enc contiguous -> one memset)
    unsigned short* feats   = (unsigned short*)(ws);                    // 67,108,864
    unsigned short* assignT = (unsigned short*)(ws + 67108864);         //  4,194,304
    unsigned short* Wb      = (unsigned short*)(ws + 71303168);         //    524,288
    unsigned short* cwb     = (unsigned short*)(ws + 71827456);         //     32,768
    float*          x2      = (float*)(ws + 71860224);                  //    262,144
    float*          asum    = (float*)(ws + 72122368);                  //      2,048
    float*          enc     = (float*)(ws + 72124416);                  //  1,048,576
    float*          sc2     = (float*)(ws + 73172992);
    float*          s1      = (float*)(ws + 73173248);
    float*          t1      = (float*)(ws + 73173504);
    float*          gamma   = (float*)(ws + 73173760);                  //     32,768

    // xT and featsT live in d_out's output region, overwritten later by k_gate
    unsigned short* xT     = (unsigned short*)((char*)d_out + 32768);     // 67,108,864
    unsigned short* featsT = (unsigned short*)((char*)d_out + 67141632);  // 67,108,864

    hipMemsetAsync(x2, 0, 262144 + 2048 + 1048576, stream);   // x2 + asum + enc

    k_prep<<<273, 256, 0, stream>>>(conv_w, cw, scale, bn1_g, bn1_b, bn1_m, bn1_v,
                                    Wb, cwb, sc2, s1, t1);
    k_transpose<<<8192, 256, 0, stream>>>(x, xT);
    k_conv_gemm<<<2048, 256, 0, stream>>>(xT, Wb, bn2_g, bn2_b, bn2_m, bn2_v,
                                          feats, featsT, x2);
    k_assign<<<512, 256, 0, stream>>>(feats, cwb, x2, scale, sc2, assignT, asum);
    k_encode<<<512, 256, 0, stream>>>(featsT, assignT, enc);
    k_efeat<<<16, 256, 0, stream>>>(enc, asum, cw, s1, t1, outf);
    k_fc<<<32, 256, 0, stream>>>(outf, fc_w, fc_b, gamma);
    k_gate<<<8192, 256, 0, stream>>>(x, gamma, outf + 8192);
}

// Round 2
// 420.484 us; speedup vs baseline: 1.0576x; 1.0312x over previous
//
#include <hip/hip_runtime.h>
#include <hip/hip_bf16.h>

// Problem constants (B, C, H, W, K) = (16, 512, 64, 64, 32)
#define BB   16
#define CC   512
#define HWN  4096        // H*W
#define KK   32
#define EPSF 1e-5f

typedef short bf16x8 __attribute__((ext_vector_type(8)));
typedef float f32x4  __attribute__((ext_vector_type(4)));

#define MFMA16 __builtin_amdgcn_mfma_f32_16x16x32_bf16

// async global->LDS, 16B per lane. LDS dest = wave-uniform base + lane*16.
#define GLD16(g, l) __builtin_amdgcn_global_load_lds(                          \
    (const __attribute__((address_space(1))) void*)(g),                        \
    (__attribute__((address_space(3))) void*)(l), 16, 0, 0)

// conv epilogue LDS tile addressing: [o][n] stride 136 shorts, 8-short chunks
// XOR-swizzled by (o>>3) so column sweeps spread across banks.
#define EADDR(o, n) ((o) * 136 + (((((n) >> 3) ^ (((o) >> 3) & 15))) << 3) + ((n) & 7))

static __device__ __forceinline__ unsigned short f2b(float f) {
    unsigned u = __builtin_bit_cast(unsigned, f);
    unsigned r = (u + 0x7FFFu + ((u >> 16) & 1u)) >> 16;   // RNE
    return (unsigned short)r;
}

// ---------------- K0: weight conversions + small precomputes ----------------
__global__ __launch_bounds__(256) void k_prep(const float* __restrict__ W,
                                              const float* __restrict__ cw,
                                              const float* __restrict__ scale,
                                              const float* __restrict__ g1,
                                              const float* __restrict__ b1,
                                              const float* __restrict__ m1,
                                              const float* __restrict__ v1,
                                              unsigned short* __restrict__ Wb,
                                              unsigned short* __restrict__ cwb,
                                              float* __restrict__ sc2,
                                              float* __restrict__ s1,
                                              float* __restrict__ t1) {
    int bid = blockIdx.x, t = threadIdx.x;
    if (bid < 256) {                       // conv_w fp32 -> bf16 (262144 elems)
        int i = (bid * 256 + t) * 4;
        float4 v = *(const float4*)(W + i);
        uint2 p;
        p.x = (unsigned)f2b(v.x) | ((unsigned)f2b(v.y) << 16);
        p.y = (unsigned)f2b(v.z) | ((unsigned)f2b(v.w) << 16);
        *(uint2*)(Wb + i) = p;
    } else if (bid < 272) {                // codewords fp32 -> bf16 (16384 elems)
        int i = ((bid - 256) * 256 + t) * 4;
        float4 v = *(const float4*)(cw + i);
        uint2 p;
        p.x = (unsigned)f2b(v.x) | ((unsigned)f2b(v.y) << 16);
        p.y = (unsigned)f2b(v.z) | ((unsigned)f2b(v.w) << 16);
        *(uint2*)(cwb + i) = p;
    } else {                               // sc2[k] = scale*||c_k||^2 ; bn1 affine
        int k = t >> 3, l8 = t & 7;
        const float* row = cw + k * CC + l8 * 64;
        float s = 0.f;
#pragma unroll
        for (int i = 0; i < 16; i++) {
            float4 c4 = *(const float4*)(row + i * 4);
            s += c4.x * c4.x + c4.y * c4.y + c4.z * c4.z + c4.w * c4.w;
        }
        s += __shfl_xor(s, 1); s += __shfl_xor(s, 2); s += __shfl_xor(s, 4);
        if (l8 == 0) sc2[k] = scale[k] * s;
        if (t < KK) {
            float sv = rsqrtf(v1[t] + EPSF) * g1[t];
            s1[t] = sv;
            t1[t] = b1[t] - m1[t] * sv;
        }
    }
}

// ---------------- K1: conv GEMM + BN2 + ReLU -> feats, featsT, x2 -----------
// Fused transpose: reads x (B,C,N fp32) directly. Per 32-c panel, each thread
// loads 2 c-rows x 8 n (4x float4, coalesced), cvt_pk to bf16 pairs, ds_write
// into transposed [n][c] LDS panel with XOR group swizzle.
// A: 2 bufs x 4096 shorts @ [0,8192); B (weights, GLD16): 3 bufs x 4096 shorts
// @ [8192,20480). One barrier per panel; vmcnt(6) keeps next panel in flight.
// Epilogue 128x136 tile (17408 shorts) reuses LDS after the loop.
#define AADDR(n, c) ((n) * 32 + (((((c) >> 3) ^ (((n) >> 3) & 3)) & 3) << 3) + ((c) & 7))

__global__ __launch_bounds__(256, 4) void k_conv_gemm(const float* __restrict__ x,
                                                      const unsigned short* __restrict__ Wb,
                                                      const float* __restrict__ g2,
                                                      const float* __restrict__ b2,
                                                      const float* __restrict__ m2,
                                                      const float* __restrict__ v2,
                                                      unsigned short* __restrict__ feats,
                                                      unsigned short* __restrict__ featsT,
                                                      float* __restrict__ x2) {
    __shared__ __align__(16) short lds[20480];
    int bid = blockIdx.x;
    // XCD-contiguous swizzle: 2048 blocks, 8 XCDs -> 256-block contiguous chunks.
    bid = (bid & 7) * 256 + (bid >> 3);
    int b   = bid >> 7;
    int rem = bid & 127;
    int m0  = (rem >> 2) * 128;   // spatial n base
    int o0  = (rem & 3) * 128;    // out-channel base fastest -> L2 reuse of x stripe
    int t = threadIdx.x, lane = t & 63, wave = t >> 6;
    int mb = (wave >> 1) * 64, ob = (wave & 1) * 64;
    int col_l = lane & 15, quad = lane >> 4;
    int pc = t >> 4;              // c-pair index 0..15 (c_local = 2*pc)
    int ch = t & 15;              // n-chunk (8 n each)

    f32x4 zero = {0.f, 0.f, 0.f, 0.f};
    f32x4 acc[4][4];
#pragma unroll
    for (int i = 0; i < 4; i++)
#pragma unroll
        for (int j = 0; j < 4; j++) acc[i][j] = zero;

    const float* Xp = x + (size_t)(b * CC) * HWN + m0 + ch * 8;
    const unsigned short* Bbase = Wb + (size_t)o0 * CC;

    float4 a0, a1, a2, a3;        // A(p+1) staging registers (2 rows x 8 n)

#define CLOAD_A(pp) do {                                                      \
    const float* r0_ = Xp + (size_t)((pp) * 32 + 2 * pc) * HWN;               \
    a0 = *(const float4*)(r0_);       a1 = *(const float4*)(r0_ + 4);         \
    a2 = *(const float4*)(r0_ + HWN); a3 = *(const float4*)(r0_ + HWN + 4);   \
} while (0)

#define CLOAD_B(pp, bb3) do {                                                 \
    int c0_ = (pp) * 32;                                                      \
    _Pragma("unroll")                                                         \
    for (int p2 = 0; p2 < 2; p2++) {                                          \
        int sbase = p2 * 256 + wave * 64;                                     \
        int s = sbase + lane;                                                 \
        GLD16(Bbase + (size_t)(s >> 2) * CC + c0_ + (s & 3) * 8,              \
              (char*)lds + 16384 + (bb3) * 8192 + sbase * 16);                \
    } } while (0)

#define CWRITE_A(ab) do {                                                     \
    unsigned q0, q1, q2, q3, q4, q5, q6, q7;                                  \
    asm("v_cvt_pk_bf16_f32 %0, %1, %2" : "=v"(q0) : "v"(a0.x), "v"(a2.x));    \
    asm("v_cvt_pk_bf16_f32 %0, %1, %2" : "=v"(q1) : "v"(a0.y), "v"(a2.y));    \
    asm("v_cvt_pk_bf16_f32 %0, %1, %2" : "=v"(q2) : "v"(a0.z), "v"(a2.z));    \
    asm("v_cvt_pk_bf16_f32 %0, %1, %2" : "=v"(q3) : "v"(a0.w), "v"(a2.w));    \
    asm("v_cvt_pk_bf16_f32 %0, %1, %2" : "=v"(q4) : "v"(a1.x), "v"(a3.x));    \
    asm("v_cvt_pk_bf16_f32 %0, %1, %2" : "=v"(q5) : "v"(a1.y), "v"(a3.y));    \
    asm("v_cvt_pk_bf16_f32 %0, %1, %2" : "=v"(q6) : "v"(a1.z), "v"(a3.z));    \
    asm("v_cvt_pk_bf16_f32 %0, %1, %2" : "=v"(q7) : "v"(a1.w), "v"(a3.w));    \
    int base_ = (ab) * 4096 + ch * 256 +                                      \
                ((((pc >> 2) ^ (ch & 3)) & 3) << 3) + ((2 * pc) & 7);         \
    *(unsigned*)(&lds[base_ +   0]) = q0;                                     \
    *(unsigned*)(&lds[base_ +  32]) = q1;                                     \
    *(unsigned*)(&lds[base_ +  64]) = q2;                                     \
    *(unsigned*)(&lds[base_ +  96]) = q3;                                     \
    *(unsigned*)(&lds[base_ + 128]) = q4;                                     \
    *(unsigned*)(&lds[base_ + 160]) = q5;                                     \
    *(unsigned*)(&lds[base_ + 192]) = q6;                                     \
    *(unsigned*)(&lds[base_ + 224]) = q7;                                     \
} while (0)

#define CCOMP(ab, bb3) do {                                                   \
    bf16x8 af[4], bfv[4];                                                     \
    _Pragma("unroll")                                                         \
    for (int im = 0; im < 4; im++) {                                          \
        int nl = mb + im * 16 + col_l;                                        \
        af[im] = *(const bf16x8*)(&lds[(ab) * 4096 + AADDR(nl, quad * 8)]);   \
    }                                                                         \
    _Pragma("unroll")                                                         \
    for (int in = 0; in < 4; in++)                                            \
        bfv[in] = *(const bf16x8*)(&lds[8192 + (bb3) * 4096 +                 \
                   (ob + in * 16 + col_l) * 32 + quad * 8]);                  \
    _Pragma("unroll")                                                         \
    for (int im = 0; im < 4; im++)                                            \
        _Pragma("unroll")                                                     \
        for (int in = 0; in < 4; in++)                                        \
            acc[im][in] = MFMA16(af[im], bfv[in], acc[im][in], 0, 0, 0);      \
    } while (0)

    // ---- prologue: establish invariant for p=0 ----
    CLOAD_A(0); CLOAD_B(0, 0);
    CWRITE_A(0);                                   // compiler waits A(0) regs
    CLOAD_A(1); CLOAD_B(1, 1);
    asm volatile("s_waitcnt lgkmcnt(0)" ::: "memory");  // my A(0) ds_writes done
    asm volatile("s_waitcnt vmcnt(6)" ::: "memory");    // B(0) landed
    __builtin_amdgcn_s_barrier();
    asm volatile("" ::: "memory");

    // ---- main loop: process p, write A(p+1), issue p+2 ----
    int bi = 0;                                    // p % 3
    for (int p = 0; p < 14; ++p) {
        CCOMP(p & 1, bi);
        CWRITE_A((p + 1) & 1);                     // compiler waits A(p+1) regs
        int bi2 = bi >= 1 ? bi - 1 : 2;            // (p+2) % 3
        CLOAD_A(p + 2); CLOAD_B(p + 2, bi2);
        asm volatile("s_waitcnt lgkmcnt(0)" ::: "memory"); // reads(p)+writes(p+1) drained
        asm volatile("s_waitcnt vmcnt(6)" ::: "memory");   // B(p+1) landed
        __builtin_amdgcn_s_barrier();
        asm volatile("" ::: "memory");
        bi = bi == 2 ? 0 : bi + 1;
    }
    // ---- peel p=14, p=15 ----
    CCOMP(0, 2);
    CWRITE_A(1);                                   // A(15)
    asm volatile("s_waitcnt lgkmcnt(0)" ::: "memory");
    asm volatile("s_waitcnt vmcnt(0)" ::: "memory");     // B(15) landed
    __builtin_amdgcn_s_barrier();
    asm volatile("" ::: "memory");
    CCOMP(1, 0);
    __syncthreads();                               // all reads done before LDS reuse

    // ---- Epilogue: BN2+ReLU; scatter to LDS tile; x2 from registers ----
    float scv[4], offv[4];
#pragma unroll
    for (int in = 0; in < 4; in++) {
        int o = o0 + ob + in * 16 + col_l;
        float sv = rsqrtf(v2[o] + EPSF) * g2[o];
        scv[in]  = sv;
        offv[in] = b2[o] - m2[o] * sv;
    }
#pragma unroll
    for (int im = 0; im < 4; im++) {
        int n_l = mb + im * 16 + quad * 4;
        float vv[4][4];
#pragma unroll
        for (int in = 0; in < 4; in++)
#pragma unroll
            for (int r = 0; r < 4; r++)
                vv[in][r] = fmaxf(acc[im][in][r] * scv[in] + offv[in], 0.f);
#pragma unroll
        for (int in = 0; in < 4; in++) {
            int o_l = ob + in * 16 + col_l;
            uint2 pk;
            pk.x = (unsigned)f2b(vv[in][0]) | ((unsigned)f2b(vv[in][1]) << 16);
            pk.y = (unsigned)f2b(vv[in][2]) | ((unsigned)f2b(vv[in][3]) << 16);
            *(uint2*)(&lds[EADDR(o_l, n_l)]) = pk;
        }
#pragma unroll
        for (int r = 0; r < 4; r++) {
            float ss = vv[0][r] * vv[0][r] + vv[1][r] * vv[1][r] +
                       vv[2][r] * vv[2][r] + vv[3][r] * vv[3][r];
            ss += __shfl_xor(ss, 1); ss += __shfl_xor(ss, 2);
            ss += __shfl_xor(ss, 4); ss += __shfl_xor(ss, 8);
            if (col_l == 0) atomicAdd(&x2[b * HWN + m0 + n_l + r], ss);
        }
    }
    __syncthreads();

    // ---- featsT sweep: coalesced 256B rows (o-major) ----
#pragma unroll
    for (int rr = 0; rr < 8; rr++) {
        int o = rr * 16 + (t >> 4);
        int n16 = t & 15;
        uint4 v = *(const uint4*)(&lds[EADDR(o, n16 * 8)]);
        *(uint4*)(featsT + (size_t)(b * CC + o0 + o) * HWN + m0 + n16 * 8) = v;
    }
    // ---- feats sweep: coalesced 256B rows (n-major) ----
#pragma unroll
    for (int rr = 0; rr < 8; rr++) {
        int n = rr * 16 + (t >> 4);
        int o16 = t & 15;
        unsigned u[4];
#pragma unroll
        for (int jj = 0; jj < 4; jj++) {
            unsigned short a = lds[EADDR(o16 * 8 + 2 * jj,     n)];
            unsigned short bsh = lds[EADDR(o16 * 8 + 2 * jj + 1, n)];
            u[jj] = (unsigned)a | ((unsigned)bsh << 16);
        }
        uint4 pk; pk.x = u[0]; pk.y = u[1]; pk.z = u[2]; pk.w = u[3];
        *(uint4*)(feats + (size_t)(b * HWN + m0 + n) * CC + o0 + o16 * 8) = pk;
    }
}

// ---------------- K2: fused xc^T GEMM + softmax -> assignT bf16, asum -------
// Pipelined: dbuf feats staging, counted vmcnt(2), raw barriers.
__global__ __launch_bounds__(256) void k_assign(const unsigned short* __restrict__ feats,
                                                const unsigned short* __restrict__ cwb,
                                                const float* __restrict__ x2,
                                                const float* __restrict__ scale,
                                                const float* __restrict__ sc2,
                                                unsigned short* __restrict__ assignT,
                                                float* __restrict__ asum) {
    // cwl (32x520 padded) @ shorts [0,16640); fl dbuf @ shorts 16640 + bb*4096
    __shared__ __align__(16) short lds2[24832];
    __shared__ float sl[KK], cl[KK];
    int bid = blockIdx.x;
    int b = bid >> 5, n0 = (bid & 31) * 128;
    int t = threadIdx.x, lane = t & 63, wave = t >> 6;
    int col_l = lane & 15, quad = lane >> 4;

    // stage all of cw (bf16, 32x512) into padded LDS once
#pragma unroll
    for (int p = 0; p < 8; p++) {
        int s = p * 256 + t;             // 2048 chunks of 8 shorts
        int row = s >> 6, c8 = (s & 63) * 8;
        *(uint4*)(&lds2[row * 520 + c8]) = *(const uint4*)(cwb + row * 512 + c8);
    }
    if (t < KK) { sl[t] = scale[t]; cl[t] = sc2[t]; }

    f32x4 zero = {0.f, 0.f, 0.f, 0.f};
    f32x4 acc[2][2];                     // [k-tile mk][n col-tile ct]
    acc[0][0] = zero; acc[0][1] = zero; acc[1][0] = zero; acc[1][1] = zero;

    const unsigned short* Fbase = feats + (size_t)(b * HWN + n0) * CC;

#define ASTAGE(ci_, bb) do {                                                  \
    int c0_ = (ci_) * 32;                                                     \
    _Pragma("unroll")                                                         \
    for (int p2 = 0; p2 < 2; p2++) {                                          \
        int sbase = p2 * 256 + wave * 64;                                     \
        int s = sbase + lane;                                                 \
        GLD16(Fbase + (size_t)(s >> 2) * CC + c0_ + (s & 3) * 8,              \
              (char*)lds2 + 33280 + (bb) * 8192 + sbase * 16);                \
    } } while (0)

#define ACOMP(ci_, bb) do {                                                   \
    int c0_ = (ci_) * 32;                                                     \
    bf16x8 af0 = *(const bf16x8*)(&lds2[(col_l) * 520 + c0_ + quad * 8]);     \
    bf16x8 af1 = *(const bf16x8*)(&lds2[(16 + col_l) * 520 + c0_ + quad * 8]);\
    _Pragma("unroll")                                                         \
    for (int ct = 0; ct < 2; ct++) {                                          \
        bf16x8 bf = *(const bf16x8*)(&lds2[16640 + (bb) * 4096 +              \
                     (wave * 32 + ct * 16 + col_l) * 32 + quad * 8]);         \
        acc[0][ct] = MFMA16(af0, bf, acc[0][ct], 0, 0, 0);                    \
        acc[1][ct] = MFMA16(af1, bf, acc[1][ct], 0, 0, 0);                    \
    } } while (0)

    ASTAGE(0, 0);
    asm volatile("s_waitcnt lgkmcnt(0)" ::: "memory");   // cwl/sl/cl writes done
    for (int ci = 0; ci < 15; ci++) {
        ASTAGE(ci + 1, (ci + 1) & 1);
        asm volatile("s_waitcnt vmcnt(2)" ::: "memory");
        __builtin_amdgcn_s_barrier();
        asm volatile("" ::: "memory");
        ACOMP(ci, ci & 1);
        asm volatile("s_waitcnt lgkmcnt(0)" ::: "memory");
        __builtin_amdgcn_s_barrier();
    }
    asm volatile("s_waitcnt vmcnt(0)" ::: "memory");
    __builtin_amdgcn_s_barrier();
    asm volatile("" ::: "memory");
    ACOMP(15, 1);

    // softmax over k per n column; write assignT; accumulate asum
    float asw[2][4];
#pragma unroll
    for (int mk = 0; mk < 2; mk++)
#pragma unroll
        for (int r = 0; r < 4; r++) asw[mk][r] = 0.f;

#pragma unroll
    for (int ct = 0; ct < 2; ct++) {
        int n = n0 + wave * 32 + ct * 16 + col_l;
        float x2v = x2[b * HWN + n];
        float d[2][4];
        float mmax = -3.4e38f;
#pragma unroll
        for (int mk = 0; mk < 2; mk++)
#pragma unroll
            for (int r = 0; r < 4; r++) {
                int k = mk * 16 + quad * 4 + r;
                d[mk][r] = sl[k] * (x2v - 2.f * acc[mk][ct][r]) + cl[k];
                mmax = fmaxf(mmax, d[mk][r]);
            }
        mmax = fmaxf(mmax, __shfl_xor(mmax, 16));
        mmax = fmaxf(mmax, __shfl_xor(mmax, 32));
        float ssum = 0.f;
#pragma unroll
        for (int mk = 0; mk < 2; mk++)
#pragma unroll
            for (int r = 0; r < 4; r++) {
                d[mk][r] = __expf(d[mk][r] - mmax);
                ssum += d[mk][r];
            }
        ssum += __shfl_xor(ssum, 16);
        ssum += __shfl_xor(ssum, 32);
        float rinv = 1.f / ssum;
#pragma unroll
        for (int mk = 0; mk < 2; mk++)
#pragma unroll
            for (int r = 0; r < 4; r++) {
                int k = mk * 16 + quad * 4 + r;
                float a = d[mk][r] * rinv;
                assignT[(size_t)(b * KK + k) * HWN + n] = f2b(a);
                float p = a;
                p += __shfl_xor(p, 1); p += __shfl_xor(p, 2);
                p += __shfl_xor(p, 4); p += __shfl_xor(p, 8);
                asw[mk][r] += p;       // valid on col_l==0 lanes
            }
    }
#pragma unroll
    for (int mk = 0; mk < 2; mk++)
#pragma unroll
        for (int r = 0; r < 4; r++)
            if (col_l == 0)
                atomicAdd(&asum[b * KK + mk * 16 + quad * 4 + r], asw[mk][r]);
}

// ---------------- K3: encode GEMM: enc[b,c,k] += sum_n a[k,n] fT[c,n] -------
// Pipelined: dbuf A/B staging (40KB), counted vmcnt(5), raw barriers.
__global__ __launch_bounds__(256) void k_encode(const unsigned short* __restrict__ featsT,
                                                const unsigned short* __restrict__ assignT,
                                                float* __restrict__ enc) {
    // Al: bytes bb*16384 + pc*8192 (2 buf x 2 panels x 8KB = 32KB)
    // Bl: bytes 32768 + bb*4096 + pc*2048 (2 buf x 2 panels x 2KB = 8KB)
    __shared__ __align__(16) short lds3[20480];
    int bid = blockIdx.x;
    int b   = bid >> 5;
    int rem = bid & 31;
    int c0  = (rem >> 3) * 128;
    int ns  = rem & 7;                   // n-split: [ns*512, ns*512+512)
    int t = threadIdx.x, lane = t & 63, wave = t >> 6;
    int col_l = lane & 15, quad = lane >> 4;

    f32x4 zero = {0.f, 0.f, 0.f, 0.f};
    f32x4 acc[2][2];                     // [c-subtile][k col-tile]
    acc[0][0] = zero; acc[0][1] = zero; acc[1][0] = zero; acc[1][1] = zero;

    const unsigned short* Abase = featsT + (size_t)(b * CC + c0) * HWN;
    const unsigned short* Bbase = assignT + (size_t)(b * KK) * HWN;

#define ESTAGE(it_, bb) do {                                                  \
    int n0_ = ns * 512 + (it_) * 64;                                          \
    _Pragma("unroll")                                                         \
    for (int pc_ = 0; pc_ < 2; pc_++)                                         \
        _Pragma("unroll")                                                     \
        for (int p2 = 0; p2 < 2; p2++) {                                      \
            int sbase = p2 * 256 + wave * 64;                                 \
            int s = sbase + lane;                                             \
            GLD16(Abase + (size_t)(s >> 2) * HWN + n0_ + pc_ * 32 + (s & 3) * 8, \
                  (char*)lds3 + (bb) * 16384 + pc_ * 8192 + sbase * 16);      \
        }                                                                     \
    {   int s = t;                                                            \
        int pan = s >> 7, row = (s & 127) >> 2, part = (s & 3) * 8;           \
        GLD16(Bbase + (size_t)row * HWN + n0_ + pan * 32 + part,              \
              (char*)lds3 + 32768 + (bb) * 4096 +                             \
              ((wave >> 1) * 2048 + (wave & 1) * 1024) + lane * 16);          \
    } } while (0)

#define ECOMP(bb) do {                                                        \
    _Pragma("unroll")                                                         \
    for (int pc_ = 0; pc_ < 2; pc_++) {                                       \
        bf16x8 a0 = *(const bf16x8*)(&lds3[(bb) * 8192 + pc_ * 4096 + (wave * 32 + col_l) * 32 + quad * 8]); \
        bf16x8 a1 = *(const bf16x8*)(&lds3[(bb) * 8192 + pc_ * 4096 + (wave * 32 + 16 + col_l) * 32 + quad * 8]); \
        bf16x8 b0 = *(const bf16x8*)(&lds3[16384 + (bb) * 2048 + pc_ * 1024 + (col_l) * 32 + quad * 8]); \
        bf16x8 b1 = *(const bf16x8*)(&lds3[16384 + (bb) * 2048 + pc_ * 1024 + (16 + col_l) * 32 + quad * 8]); \
        acc[0][0] = MFMA16(a0, b0, acc[0][0], 0, 0, 0);                       \
        acc[0][1] = MFMA16(a0, b1, acc[0][1], 0, 0, 0);                       \
        acc[1][0] = MFMA16(a1, b0, acc[1][0], 0, 0, 0);                       \
        acc[1][1] = MFMA16(a1, b1, acc[1][1], 0, 0, 0);                       \
    } } while (0)

    ESTAGE(0, 0);
    for (int it = 0; it < 7; it++) {
        ESTAGE(it + 1, (it + 1) & 1);
        asm volatile("s_waitcnt vmcnt(5)" ::: "memory");
        __builtin_amdgcn_s_barrier();
        asm volatile("" ::: "memory");
        ECOMP(it & 1);
        asm volatile("s_waitcnt lgkmcnt(0)" ::: "memory");
        __builtin_amdgcn_s_barrier();
    }
    asm volatile("s_waitcnt vmcnt(0)" ::: "memory");
    __builtin_amdgcn_s_barrier();
    asm volatile("" ::: "memory");
    ECOMP(1);

#pragma unroll
    for (int i2 = 0; i2 < 2; i2++)
#pragma unroll
        for (int ck = 0; ck < 2; ck++)
#pragma unroll
            for (int r = 0; r < 4; r++) {
                int c = c0 + wave * 32 + i2 * 16 + quad * 4 + r;
                int k = ck * 16 + col_l;
                atomicAdd(&enc[(size_t)(b * CC + c) * KK + k], acc[i2][ck][r]);
            }
}

// ---------------- K3b: BN1 + ReLU + mean over k -> efeat --------------------
__global__ __launch_bounds__(256) void k_efeat(const float* __restrict__ enc,
                                               const float* __restrict__ asum,
                                               const float* __restrict__ cwf,
                                               const float* __restrict__ s1,
                                               const float* __restrict__ t1,
                                               float* __restrict__ efeat) {
    __shared__ float asl[KK], s1l[KK], t1l[KK];
    int b = blockIdx.x, t = threadIdx.x;
    if (t < KK) { asl[t] = asum[b * KK + t]; s1l[t] = s1[t]; t1l[t] = t1[t]; }
    __syncthreads();
#pragma unroll
    for (int cc = 0; cc < 2; cc++) {
        int c = cc * 256 + t;
        const float* er = enc + (size_t)(b * CC + c) * KK;
        float s = 0.f;
#pragma unroll
        for (int k = 0; k < KK; k++) {
            float v = (er[k] - asl[k] * cwf[k * CC + c]) * s1l[k] + t1l[k];
            s += fmaxf(v, 0.f);
        }
        efeat[b * CC + c] = s * (1.f / 32.f);
    }
}

// ---------------- K4: gamma = sigmoid(efeat @ fc_w^T + fc_b) ----------------
__global__ __launch_bounds__(256) void k_fc(const float* __restrict__ efeat,
                                            const float* __restrict__ fcw,
                                            const float* __restrict__ fcb,
                                            float* __restrict__ gamma) {
    __shared__ float ef[CC];
    int bid = blockIdx.x;
    int b  = bid >> 1;
    int o0 = (bid & 1) * 256;
    int t = threadIdx.x;
    if (t < 128) *(float4*)(&ef[t * 4]) = *(const float4*)(efeat + b * CC + t * 4);
    __syncthreads();
    int o = o0 + t;
    float a = fcb[o];
    const float* wrow = fcw + (size_t)o * CC;
#pragma unroll 4
    for (int c4 = 0; c4 < 128; c4++) {
        float4 w = *(const float4*)(wrow + c4 * 4);
        float4 e = *(const float4*)(&ef[c4 * 4]);
        a += w.x * e.x + w.y * e.y + w.z * e.z + w.w * e.w;
    }
    gamma[b * CC + o] = 1.f / (1.f + __expf(-a));
}

// ---------------- K5: out = relu(x * (1 + gamma[b,c])) ----------------------
// one block per (b,c) row of 4096 floats
__global__ __launch_bounds__(256) void k_gate(const float* __restrict__ x,
                                              const float* __restrict__ gamma,
                                              float* __restrict__ out) {
    int bid = blockIdx.x;                // bid = b*512 + c
    float g = 1.f + gamma[bid];
    const float* xr = x + ((size_t)bid << 12);
    float* orow = out + ((size_t)bid << 12);
    int t4 = threadIdx.x * 4;
#pragma unroll
    for (int u = 0; u < 4; u++) {
        float4 v = *(const float4*)(xr + u * 1024 + t4);
        v.x = fmaxf(v.x * g, 0.f);
        v.y = fmaxf(v.y * g, 0.f);
        v.z = fmaxf(v.z * g, 0.f);
        v.w = fmaxf(v.w * g, 0.f);
        *(float4*)(orow + u * 1024 + t4) = v;
    }
}

extern "C" void kernel_launch(void* const* d_in, const int* in_sizes, int n_in,
                              void* d_out, int out_size, void* d_ws, size_t ws_size,
                              hipStream_t stream) {
    const float* x      = (const float*)d_in[0];
    const float* conv_w = (const float*)d_in[1];
    const float* bn2_g  = (const float*)d_in[2];
    const float* bn2_b  = (const float*)d_in[3];
    const float* bn2_m  = (const float*)d_in[4];
    const float* bn2_v  = (const float*)d_in[5];
    const float* cw     = (const float*)d_in[6];
    const float* scale  = (const float*)d_in[7];
    const float* bn1_g  = (const float*)d_in[8];
    const float* bn1_b  = (const float*)d_in[9];
    const float* bn1_m  = (const float*)d_in[10];
    const float* bn1_v  = (const float*)d_in[11];
    const float* fc_w   = (const float*)d_in[12];
    const float* fc_b   = (const float*)d_in[13];

    float* outf = (float*)d_out;               // [0,8192) efeat, [8192,...) gated output
    char* ws = (char*)d_ws;

    // workspace layout (x2/asum/enc contiguous -> one memset)
    unsigned short* feats   = (unsigned short*)(ws);                    // 67,108,864
    unsigned short* assignT = (unsigned short*)(ws + 67108864);         //  4,194,304
    unsigned short* Wb      = (unsigned short*)(ws + 71303168);         //    524,288
    unsigned short* cwb     = (unsigned short*)(ws + 71827456);         //     32,768
    float*          x2      = (float*)(ws + 71860224);                  //    262,144
    float*          asum    = (float*)(ws + 72122368);                  //      2,048
    float*          enc     = (float*)(ws + 72124416);                  //  1,048,576
    float*          sc2     = (float*)(ws + 73172992);
    float*          s1      = (float*)(ws + 73173248);
    float*          t1      = (float*)(ws + 73173504);
    float*          gamma   = (float*)(ws + 73173760);                  //     32,768

    // featsT lives in d_out's output region, overwritten later by k_gate
    unsigned short* featsT = (unsigned short*)((char*)d_out + 67141632);  // 67,108,864

    hipMemsetAsync(x2, 0, 262144 + 2048 + 1048576, stream);   // x2 + asum + enc

    k_prep<<<273, 256, 0, stream>>>(conv_w, cw, scale, bn1_g, bn1_b, bn1_m, bn1_v,
                                    Wb, cwb, sc2, s1, t1);
    k_conv_gemm<<<2048, 256, 0, stream>>>(x, Wb, bn2_g, bn2_b, bn2_m, bn2_v,
                                          feats, featsT, x2);
    k_assign<<<512, 256, 0, stream>>>(feats, cwb, x2, scale, sc2, assignT, asum);
    k_encode<<<512, 256, 0, stream>>>(featsT, assignT, enc);
    k_efeat<<<16, 256, 0, stream>>>(enc, asum, cw, s1, t1, outf);
    k_fc<<<32, 256, 0, stream>>>(outf, fc_w, fc_b, gamma);
    k_gate<<<8192, 256, 0, stream>>>(x, gamma, outf + 8192);
}